// Round 3
// baseline (1489.434 us; speedup 1.0000x reference)
//
#include <hip/hip_runtime.h>

// ---------------------------------------------------------------------------
// All four projections in one launch. 4 rows per block, 128 threads.
// CHUNKED=0: Y[((bb*8+h)*L + l)*16 + dd]                      (row layout, V)
// CHUNKED=1: Y[(((bb*8+h)*4 + dd/4)*L + l)*4 + dd%4]   (chunk-major, Q and K)
// ---------------------------------------------------------------------------
__global__ __launch_bounds__(128) void proj_all_kernel(
    const float* __restrict__ q, const float* __restrict__ k,
    const float* __restrict__ v, const float* __restrict__ v2,
    const float* __restrict__ W_Q, const float* __restrict__ b_Q,
    const float* __restrict__ W_K, const float* __restrict__ b_K,
    const float* __restrict__ W_V, const float* __restrict__ b_V,
    const float* __restrict__ W_V2, const float* __restrict__ b_V2,
    float* __restrict__ Qp, float* __restrict__ Kp,
    float* __restrict__ Vp, float* __restrict__ V2p)
{
  __shared__ float xs[4][128];
  int blk = blockIdx.x;
  const float *X, *W, *B; float* Y; int L, chunked, rb;
  if (blk < 1024)      { X = q;  W = W_Q;  B = b_Q;  Y = Qp;  L = 1024; chunked = 1; rb = blk; }
  else if (blk < 3072) { X = k;  W = W_K;  B = b_K;  Y = Kp;  L = 2048; chunked = 1; rb = blk - 1024; }
  else if (blk < 5120) { X = v;  W = W_V;  B = b_V;  Y = Vp;  L = 2048; chunked = 0; rb = blk - 3072; }
  else                 { X = v2; W = W_V2; B = b_V2; Y = V2p; L = 1024; chunked = 0; rb = blk - 5120; }
  rb *= 4;
  int c = threadIdx.x;
#pragma unroll
  for (int i = 0; i < 4; ++i)
    xs[i][c] = X[(size_t)(rb + i) * 128 + c];
  __syncthreads();
  float b = B[c];
  float a0 = b, a1 = b, a2 = b, a3 = b;
#pragma unroll 8
  for (int d = 0; d < 128; ++d) {
    float w = W[d * 128 + c];
    a0 = fmaf(xs[0][d], w, a0);
    a1 = fmaf(xs[1][d], w, a1);
    a2 = fmaf(xs[2][d], w, a2);
    a3 = fmaf(xs[3][d], w, a3);
  }
  int h = c >> 4, dd = c & 15;
  float av[4] = { a0, a1, a2, a3 };
#pragma unroll
  for (int i = 0; i < 4; ++i) {
    int row = rb + i;
    int bb = row / L;
    int l  = row - bb * L;
    if (chunked)
      Y[(((size_t)(bb * 8 + h) * 4 + (dd >> 2)) * L + l) * 4 + (dd & 3)] = av[i];
    else
      Y[((size_t)(bb * 8 + h) * L + l) * 16 + dd] = av[i];
  }
}

// Guarded hybrid root step for f(u-shifted) = S2 - 1 over current support:
// exact segment root when discriminant real, else Newton.
static __device__ __forceinline__ float hstep(float f, float s1, float cnt)
{
  float arg = fmaf(-cnt, f, s1 * s1);
  return (arg > 0.f) ? f / (s1 + sqrtf(arg)) : f / (2.f * s1);
}

// ---------------------------------------------------------------------------
// Attention pass (fp32). ONE WAVE PER ROW (persistent state = x[J] + qf[16]
// -> VGPR fits 6 waves/SIMD with __launch_bounds__(256,6); 2x the latency
// hiding of the 2-row variant). Scores in registers (k = lane + 64*j).
// RowM/ColM chunk-major so score loads are 16B/lane contiguous. Support
// counts via __ballot -> SGPR. Once support <= CAP, survivors compacted to
// per-wave LDS; compacted solver + sparse P@V use all 64 lanes on the row.
// ---------------------------------------------------------------------------
template<int LROW, int LCOL>
__global__ __launch_bounds__(256, 6) void attn_kernel(
    const float* __restrict__ RowM, const float* __restrict__ ColM,
    const float* __restrict__ ValM, float* __restrict__ Aout,
    float* __restrict__ OutWs)
{
  constexpr int J   = LCOL / 64;
  constexpr int CAP = 512;
  __shared__ float          sval[4][CAP];
  __shared__ unsigned short sidx[4][CAP];

  int ws   = threadIdx.x >> 6;                      // wave slot in block
  int wid  = blockIdx.x * 4 + ws;                   // global row id
  int lane = threadIdx.x & 63;
  int bh   = wid / LROW;
  int r    = wid - bh * LROW;
  int bb   = bh >> 3, h = bh & 7;

  float qf[16];
  { const float* qb = RowM + (size_t)bh * LROW * 16;   // chunk-major block
#pragma unroll
    for (int d = 0; d < 16; ++d)
      qf[d] = qb[((size_t)(d >> 2) * LROW + r) * 4 + (d & 3)] * 0.125f;
  }

  // -------- scores (raw; max folded into tau0) --------
  float x[J];
  const float4* Cb = (const float4*)(ColM + (size_t)bh * LCOL * 16);
#pragma unroll
  for (int j = 0; j < J; ++j) {
    int kk = lane + 64 * j;
    float4 k0 = Cb[0 * LCOL + kk];      // 16B/lane contiguous -> 1KB/wave
    float  s  = qf[0] * k0.x;
    s = fmaf(qf[1], k0.y, s); s = fmaf(qf[2], k0.z, s); s = fmaf(qf[3], k0.w, s);
    float4 k1 = Cb[1 * LCOL + kk];
    s = fmaf(qf[4], k1.x, s); s = fmaf(qf[5], k1.y, s);
    s = fmaf(qf[6], k1.z, s); s = fmaf(qf[7], k1.w, s);
    float4 k2 = Cb[2 * LCOL + kk];
    s = fmaf(qf[8], k2.x, s); s = fmaf(qf[9], k2.y, s);
    s = fmaf(qf[10], k2.z, s); s = fmaf(qf[11], k2.w, s);
    float4 k3 = Cb[3 * LCOL + kk];
    s = fmaf(qf[12], k3.x, s); s = fmaf(qf[13], k3.y, s);
    s = fmaf(qf[14], k3.z, s); s = fmaf(qf[15], k3.w, s);
    x[j] = s;
  }

  float m = -1e30f;
#pragma unroll
  for (int j = 0; j < J; ++j) m = fmaxf(m, x[j]);
#pragma unroll
  for (int off = 32; off >= 1; off >>= 1)
    m = fmaxf(m, __shfl_xor(m, off));

  float tau = m - 1.0f;

  // -------- full-register sweeps until converged or compactable --------
  bool done = false;
  bool compactable = false;
  for (int it = 0; it < 24; ++it) {
    float a1 = 0.f, a2 = 0.f;
    int ac = 0;                               // wave-uniform (ballot/popc)
#pragma unroll
    for (int j = 0; j < J; ++j) {
      float t = x[j] - tau, r0 = fmaxf(t, 0.f);
      a1 += r0; a2 = fmaf(r0, r0, a2);
      ac += __popcll(__ballot(t > 0.f));
    }
#pragma unroll
    for (int off = 32; off >= 1; off >>= 1) {
      a1 += __shfl_xor(a1, off);
      a2 += __shfl_xor(a2, off);
    }
    float f = a2 - 1.0f;
    bool g = !done && (f > 1e-6f) && (a1 > 1e-12f);
    if (g) tau += hstep(f, a1, (float)ac); else done = true;
    if (ac <= CAP) { compactable = true; break; }
    if (done) break;
  }

  float* arow = Aout + ((size_t)bh * LROW + r) * LCOL;
  const float* Vb = ValM + (size_t)bh * LCOL * 16;
  float* op = OutWs + ((size_t)bb * LROW + r) * 128 + h * 16;

  if (compactable) {
    // -------- compact survivors via wave prefix-sum --------
    int c = 0;
#pragma unroll
    for (int j = 0; j < J; ++j) c += (x[j] > tau) ? 1 : 0;
    int i = c;
#pragma unroll
    for (int off = 1; off <= 32; off <<= 1) {
      int t = __shfl_up(i, off);
      if (lane >= off) i += t;
    }
    int base = i - c;
    int tot  = __shfl(i, 63);
    int w = 0;
#pragma unroll
    for (int j = 0; j < J; ++j) {
      if (x[j] > tau) {
        sval[ws][base + w] = x[j];
        sidx[ws][base + w] = (unsigned short)(lane + 64 * j);
        ++w;
      }
    }
    __threadfence_block();   // wave-local LDS visibility across lanes

    // -------- compacted solver (<=8 elems/lane) --------
    if (!done) {
      for (int it = 0; it < 24; ++it) {
        float s1 = 0.f, s2 = 0.f;
        int cnt = 0;
        for (int i2 = lane; i2 < tot; i2 += 64) {
          float t = sval[ws][i2] - tau, r0 = fmaxf(t, 0.f);
          s1 += r0; s2 = fmaf(r0, r0, s2);
          cnt += __popcll(__ballot(t > 0.f));
        }
#pragma unroll
        for (int off = 32; off >= 1; off >>= 1) {
          s1 += __shfl_xor(s1, off);
          s2 += __shfl_xor(s2, off);
        }
        float f = s2 - 1.0f;
        bool g = (f > 1e-6f) && (s1 > 1e-12f);
        if (g) tau += hstep(f, s1, (float)cnt); else { done = true; break; }
      }
    }

    // -------- dense A write from live score registers (coalesced) --------
#pragma unroll
    for (int j = 0; j < J; ++j) {
      int kk = lane + 64 * j;
      float t = fmaxf(x[j] - tau, 0.f);
      arow[kk] = t * t;
    }

    // -------- sparse P@V over survivors (all 64 lanes on this row) -------
    float acc[16];
#pragma unroll
    for (int d = 0; d < 16; ++d) acc[d] = 0.f;
    for (int i2 = lane; i2 < tot; i2 += 64) {
      float t = sval[ws][i2] - tau;
      if (t > 0.f) {
        float p = t * t;
        int kk = sidx[ws][i2];
        const float4* vp = (const float4*)(Vb + (size_t)kk * 16);
        float4 v0 = vp[0], v1 = vp[1], v2 = vp[2], v3 = vp[3];
        acc[0]  = fmaf(p, v0.x, acc[0]);  acc[1]  = fmaf(p, v0.y, acc[1]);
        acc[2]  = fmaf(p, v0.z, acc[2]);  acc[3]  = fmaf(p, v0.w, acc[3]);
        acc[4]  = fmaf(p, v1.x, acc[4]);  acc[5]  = fmaf(p, v1.y, acc[5]);
        acc[6]  = fmaf(p, v1.z, acc[6]);  acc[7]  = fmaf(p, v1.w, acc[7]);
        acc[8]  = fmaf(p, v2.x, acc[8]);  acc[9]  = fmaf(p, v2.y, acc[9]);
        acc[10] = fmaf(p, v2.z, acc[10]); acc[11] = fmaf(p, v2.w, acc[11]);
        acc[12] = fmaf(p, v3.x, acc[12]); acc[13] = fmaf(p, v3.y, acc[13]);
        acc[14] = fmaf(p, v3.z, acc[14]); acc[15] = fmaf(p, v3.w, acc[15]);
      }
    }
#pragma unroll
    for (int off = 32; off >= 1; off >>= 1)
#pragma unroll
      for (int d = 0; d < 16; ++d) acc[d] += __shfl_xor(acc[d], off);
    float vv = acc[0];
#pragma unroll
    for (int d = 1; d < 16; ++d)
      vv = (lane == d) ? acc[d] : vv;
    if (lane < 16) op[lane] = vv;
    return;
  }

  // -------- fallback: dense A write + dense P@V (large-support rows) -----
  float acc[16];
#pragma unroll
  for (int d = 0; d < 16; ++d) acc[d] = 0.f;
#pragma unroll
  for (int j = 0; j < J; ++j) {
    int kk = lane + 64 * j;
    float t = fmaxf(x[j] - tau, 0.f), p = t * t;
    arow[kk] = p;
    const float4* vp = (const float4*)(Vb + (size_t)kk * 16);
    float4 v0 = vp[0], v1 = vp[1], v2 = vp[2], v3 = vp[3];
    acc[0]  = fmaf(p, v0.x, acc[0]);  acc[1]  = fmaf(p, v0.y, acc[1]);
    acc[2]  = fmaf(p, v0.z, acc[2]);  acc[3]  = fmaf(p, v0.w, acc[3]);
    acc[4]  = fmaf(p, v1.x, acc[4]);  acc[5]  = fmaf(p, v1.y, acc[5]);
    acc[6]  = fmaf(p, v1.z, acc[6]);  acc[7]  = fmaf(p, v1.w, acc[7]);
    acc[8]  = fmaf(p, v2.x, acc[8]);  acc[9]  = fmaf(p, v2.y, acc[9]);
    acc[10] = fmaf(p, v2.z, acc[10]); acc[11] = fmaf(p, v2.w, acc[11]);
    acc[12] = fmaf(p, v3.x, acc[12]); acc[13] = fmaf(p, v3.y, acc[13]);
    acc[14] = fmaf(p, v3.z, acc[14]); acc[15] = fmaf(p, v3.w, acc[15]);
  }
#pragma unroll
  for (int off = 32; off >= 1; off >>= 1)
#pragma unroll
    for (int d = 0; d < 16; ++d) acc[d] += __shfl_xor(acc[d], off);
  float vv = acc[0];
#pragma unroll
  for (int d = 1; d < 16; ++d)
    vv = (lane == d) ? acc[d] : vv;
  if (lane < 16) op[lane] = vv;
}

// ---------------------------------------------------------------------------
// Fused: Y = X1 @ W1 + bias + X2 @ W2, then LayerNorm(gamma,beta) + ReLU.
// 4 rows per block, 128 threads (one output column each, 2 waves).
// ---------------------------------------------------------------------------
__global__ __launch_bounds__(128) void combine_ln_kernel(
    const float* __restrict__ X1, const float* __restrict__ X2,
    const float* __restrict__ W1, const float* __restrict__ W2,
    const float* __restrict__ bias, const float* __restrict__ gamma,
    const float* __restrict__ beta, float* __restrict__ O)
{
  __shared__ float x1s[4][128], x2s[4][128];
  __shared__ float red[2][8];
  int rb = blockIdx.x * 4;
  int c  = threadIdx.x;
#pragma unroll
  for (int i = 0; i < 4; ++i) {
    x1s[i][c] = X1[(size_t)(rb + i) * 128 + c];
    x2s[i][c] = X2[(size_t)(rb + i) * 128 + c];
  }
  __syncthreads();
  float b = bias[c];
  float a0 = b, a1 = b, a2 = b, a3 = b;
#pragma unroll 4
  for (int d = 0; d < 128; ++d) {
    float w1 = W1[d * 128 + c];
    float w2 = W2[d * 128 + c];
    a0 = fmaf(x1s[0][d], w1, fmaf(x2s[0][d], w2, a0));
    a1 = fmaf(x1s[1][d], w1, fmaf(x2s[1][d], w2, a1));
    a2 = fmaf(x1s[2][d], w1, fmaf(x2s[2][d], w2, a2));
    a3 = fmaf(x1s[3][d], w1, fmaf(x2s[3][d], w2, a3));
  }
  float s0 = a0, s1 = a1, s2 = a2, s3 = a3;
  float q0 = a0 * a0, q1 = a1 * a1, q2 = a2 * a2, q3 = a3 * a3;
#pragma unroll
  for (int off = 32; off >= 1; off >>= 1) {
    s0 += __shfl_xor(s0, off); q0 += __shfl_xor(q0, off);
    s1 += __shfl_xor(s1, off); q1 += __shfl_xor(q1, off);
    s2 += __shfl_xor(s2, off); q2 += __shfl_xor(q2, off);
    s3 += __shfl_xor(s3, off); q3 += __shfl_xor(q3, off);
  }
  int wv = c >> 6;
  if ((c & 63) == 0) {
    red[wv][0] = s0; red[wv][1] = q0; red[wv][2] = s1; red[wv][3] = q1;
    red[wv][4] = s2; red[wv][5] = q2; red[wv][6] = s3; red[wv][7] = q3;
  }
  __syncthreads();
  float S0 = red[0][0] + red[1][0], Q0 = red[0][1] + red[1][1];
  float S1 = red[0][2] + red[1][2], Q1 = red[0][3] + red[1][3];
  float S2 = red[0][4] + red[1][4], Q2 = red[0][5] + red[1][5];
  float S3 = red[0][6] + red[1][6], Q3 = red[0][7] + red[1][7];
  float g = gamma[c], be = beta[c];
  float mu, var, rs;
  mu = S0 * (1.f / 128.f); var = fmaxf(Q0 * (1.f / 128.f) - mu * mu, 0.f);
  rs = rsqrtf(var + 1e-5f);
  O[(size_t)(rb + 0) * 128 + c] = fmaxf(fmaf((a0 - mu) * rs, g, be), 0.f);
  mu = S1 * (1.f / 128.f); var = fmaxf(Q1 * (1.f / 128.f) - mu * mu, 0.f);
  rs = rsqrtf(var + 1e-5f);
  O[(size_t)(rb + 1) * 128 + c] = fmaxf(fmaf((a1 - mu) * rs, g, be), 0.f);
  mu = S2 * (1.f / 128.f); var = fmaxf(Q2 * (1.f / 128.f) - mu * mu, 0.f);
  rs = rsqrtf(var + 1e-5f);
  O[(size_t)(rb + 2) * 128 + c] = fmaxf(fmaf((a2 - mu) * rs, g, be), 0.f);
  mu = S3 * (1.f / 128.f); var = fmaxf(Q3 * (1.f / 128.f) - mu * mu, 0.f);
  rs = rsqrtf(var + 1e-5f);
  O[(size_t)(rb + 3) * 128 + c] = fmaxf(fmaf((a3 - mu) * rs, g, be), 0.f);
}

// ---------------------------------------------------------------------------
extern "C"
__attribute__((visibility("default"), used))
void kernel_launch(void* const* d_in, const int* in_sizes, int n_in,
                   void* d_out, int out_size, void* d_ws, size_t ws_size,
                   hipStream_t stream)
{
  (void)in_sizes; (void)n_in; (void)out_size; (void)ws_size;
  const float* q     = (const float*)d_in[0];
  const float* k     = (const float*)d_in[1];
  const float* v     = (const float*)d_in[2];
  const float* v2    = (const float*)d_in[3];
  const float* W_Q   = (const float*)d_in[4];
  const float* b_Q   = (const float*)d_in[5];
  const float* W_K   = (const float*)d_in[6];
  const float* b_K   = (const float*)d_in[7];
  const float* W_V   = (const float*)d_in[8];
  const float* b_V   = (const float*)d_in[9];
  const float* W_V2  = (const float*)d_in[10];
  const float* b_V2  = (const float*)d_in[11];
  const float* W_O   = (const float*)d_in[12];
  const float* b_O   = (const float*)d_in[13];
  const float* W_O2  = (const float*)d_in[14];
  const float* b_O2  = (const float*)d_in[15];
  const float* W_R   = (const float*)d_in[16];
  const float* W_R2  = (const float*)d_in[17];
  const float* gamma = (const float*)d_in[18];
  const float* beta  = (const float*)d_in[19];

  char* ws = (char*)d_ws;
  const size_t MB = 1u << 20;
  float* Qp    = (float*)(ws + 0);        // chunk-major [bh][4][1024][4]
  float* Kp    = (float*)(ws + 2 * MB);   // chunk-major [bh][4][2048][4]
  float* Vp    = (float*)(ws + 6 * MB);   // row-major   [bh][2048][16]
  float* V2p   = (float*)(ws + 10 * MB);  // row-major   [bh][1024][16]
  float* outm1 = (float*)(ws + 12 * MB);
  float* outm2 = (float*)(ws + 14 * MB);

  float* out1  = (float*)d_out;              // (4,1024,128)
  float* out2  = out1 + (size_t)524288;      // (4,2048,128)
  float* Aout  = out1 + (size_t)1572864;     // (4,8,1024,2048)
  float* A2out = out1 + (size_t)68681728;    // (4,8,2048,1024)

  proj_all_kernel<<<6144, 128, 0, stream>>>(
      q, k, v, v2, W_Q, b_Q, W_K, b_K, W_V, b_V, W_V2, b_V2,
      Qp, Kp, Vp, V2p);

  attn_kernel<1024, 2048><<<8192,  256, 0, stream>>>(Qp, Kp, Vp,  Aout,  outm1);
  attn_kernel<2048, 1024><<<16384, 256, 0, stream>>>(Kp, Qp, V2p, A2out, outm2);

  combine_ln_kernel<<<1024, 128, 0, stream>>>(outm1, q, W_O,  W_R,  b_O,
                                              gamma, beta, out1);
  combine_ln_kernel<<<2048, 128, 0, stream>>>(outm2, k, W_O2, W_R2, b_O2,
                                              gamma, beta, out2);
}

// Round 4
// 1196.881 us; speedup vs baseline: 1.2444x; 1.2444x over previous
//
#include <hip/hip_runtime.h>

// ---------------------------------------------------------------------------
// All four projections in one launch. 4 rows per block, 128 threads.
// CHUNKED=0: Y[((bb*8+h)*L + l)*16 + dd]                      (row layout, V)
// CHUNKED=1: Y[(((bb*8+h)*4 + dd/4)*L + l)*4 + dd%4]   (chunk-major, Q and K)
// ---------------------------------------------------------------------------
__global__ __launch_bounds__(128) void proj_all_kernel(
    const float* __restrict__ q, const float* __restrict__ k,
    const float* __restrict__ v, const float* __restrict__ v2,
    const float* __restrict__ W_Q, const float* __restrict__ b_Q,
    const float* __restrict__ W_K, const float* __restrict__ b_K,
    const float* __restrict__ W_V, const float* __restrict__ b_V,
    const float* __restrict__ W_V2, const float* __restrict__ b_V2,
    float* __restrict__ Qp, float* __restrict__ Kp,
    float* __restrict__ Vp, float* __restrict__ V2p)
{
  __shared__ float xs[4][128];
  int blk = blockIdx.x;
  const float *X, *W, *B; float* Y; int L, chunked, rb;
  if (blk < 1024)      { X = q;  W = W_Q;  B = b_Q;  Y = Qp;  L = 1024; chunked = 1; rb = blk; }
  else if (blk < 3072) { X = k;  W = W_K;  B = b_K;  Y = Kp;  L = 2048; chunked = 1; rb = blk - 1024; }
  else if (blk < 5120) { X = v;  W = W_V;  B = b_V;  Y = Vp;  L = 2048; chunked = 0; rb = blk - 3072; }
  else                 { X = v2; W = W_V2; B = b_V2; Y = V2p; L = 1024; chunked = 0; rb = blk - 5120; }
  rb *= 4;
  int c = threadIdx.x;
#pragma unroll
  for (int i = 0; i < 4; ++i)
    xs[i][c] = X[(size_t)(rb + i) * 128 + c];
  __syncthreads();
  float b = B[c];
  float a0 = b, a1 = b, a2 = b, a3 = b;
#pragma unroll 8
  for (int d = 0; d < 128; ++d) {
    float w = W[d * 128 + c];
    a0 = fmaf(xs[0][d], w, a0);
    a1 = fmaf(xs[1][d], w, a1);
    a2 = fmaf(xs[2][d], w, a2);
    a3 = fmaf(xs[3][d], w, a3);
  }
  int h = c >> 4, dd = c & 15;
  float av[4] = { a0, a1, a2, a3 };
#pragma unroll
  for (int i = 0; i < 4; ++i) {
    int row = rb + i;
    int bb = row / L;
    int l  = row - bb * L;
    if (chunked)
      Y[(((size_t)(bb * 8 + h) * 4 + (dd >> 2)) * L + l) * 4 + (dd & 3)] = av[i];
    else
      Y[((size_t)(bb * 8 + h) * L + l) * 16 + dd] = av[i];
  }
}

// Guarded hybrid root step for f(u-shifted) = S2 - 1 over current support:
// exact segment root when discriminant real, else Newton.
static __device__ __forceinline__ float hstep(float f, float s1, float cnt)
{
  float arg = fmaf(-cnt, f, s1 * s1);
  return (arg > 0.f) ? f / (s1 + sqrtf(arg)) : f / (2.f * s1);
}

// ---------------------------------------------------------------------------
// Attention pass (fp32). ONE WAVE PER ROW. MINW = min waves/SIMD: chosen so
// the VGPR cap comfortably exceeds natural usage (attn1 J=32 needs ~100 ->
// MINW=4 cap 128; attn2 J=16 needs ~70 -> MINW=5 cap 102). Round-3 lesson:
// MINW=6 (cap 85) forced scratch spills of x[] -> 1.5 GB/dispatch of HBM
// spill traffic. NEVER cap below natural usage.
// Scores in registers (k = lane + 64*j); RowM/ColM chunk-major so score
// loads are 16B/lane contiguous. Support counts via __ballot -> SGPR.
// Once support <= CAP, survivors compacted to per-wave LDS; compacted
// solver + sparse P@V use all 64 lanes on the row.
// ---------------------------------------------------------------------------
template<int LROW, int LCOL, int MINW>
__global__ __launch_bounds__(256, MINW) void attn_kernel(
    const float* __restrict__ RowM, const float* __restrict__ ColM,
    const float* __restrict__ ValM, float* __restrict__ Aout,
    float* __restrict__ OutWs)
{
  constexpr int J   = LCOL / 64;
  constexpr int CAP = 512;
  __shared__ float          sval[4][CAP];
  __shared__ unsigned short sidx[4][CAP];

  int ws   = threadIdx.x >> 6;                      // wave slot in block
  int wid  = blockIdx.x * 4 + ws;                   // global row id
  int lane = threadIdx.x & 63;
  int bh   = wid / LROW;
  int r    = wid - bh * LROW;
  int bb   = bh >> 3, h = bh & 7;

  float qf[16];
  { const float* qb = RowM + (size_t)bh * LROW * 16;   // chunk-major block
#pragma unroll
    for (int d = 0; d < 16; ++d)
      qf[d] = qb[((size_t)(d >> 2) * LROW + r) * 4 + (d & 3)] * 0.125f;
  }

  // -------- scores (raw; max folded into tau0) --------
  float x[J];
  const float4* Cb = (const float4*)(ColM + (size_t)bh * LCOL * 16);
#pragma unroll
  for (int j = 0; j < J; ++j) {
    int kk = lane + 64 * j;
    float4 k0 = Cb[0 * LCOL + kk];      // 16B/lane contiguous -> 1KB/wave
    float  s  = qf[0] * k0.x;
    s = fmaf(qf[1], k0.y, s); s = fmaf(qf[2], k0.z, s); s = fmaf(qf[3], k0.w, s);
    float4 k1 = Cb[1 * LCOL + kk];
    s = fmaf(qf[4], k1.x, s); s = fmaf(qf[5], k1.y, s);
    s = fmaf(qf[6], k1.z, s); s = fmaf(qf[7], k1.w, s);
    float4 k2 = Cb[2 * LCOL + kk];
    s = fmaf(qf[8], k2.x, s); s = fmaf(qf[9], k2.y, s);
    s = fmaf(qf[10], k2.z, s); s = fmaf(qf[11], k2.w, s);
    float4 k3 = Cb[3 * LCOL + kk];
    s = fmaf(qf[12], k3.x, s); s = fmaf(qf[13], k3.y, s);
    s = fmaf(qf[14], k3.z, s); s = fmaf(qf[15], k3.w, s);
    x[j] = s;
  }

  float m = -1e30f;
#pragma unroll
  for (int j = 0; j < J; ++j) m = fmaxf(m, x[j]);
#pragma unroll
  for (int off = 32; off >= 1; off >>= 1)
    m = fmaxf(m, __shfl_xor(m, off));

  float tau = m - 1.0f;

  // -------- full-register sweeps until converged or compactable --------
  bool done = false;
  bool compactable = false;
  for (int it = 0; it < 24; ++it) {
    float a1 = 0.f, a2 = 0.f;
    int ac = 0;                               // wave-uniform (ballot/popc)
#pragma unroll
    for (int j = 0; j < J; ++j) {
      float t = x[j] - tau, r0 = fmaxf(t, 0.f);
      a1 += r0; a2 = fmaf(r0, r0, a2);
      ac += __popcll(__ballot(t > 0.f));
    }
#pragma unroll
    for (int off = 32; off >= 1; off >>= 1) {
      a1 += __shfl_xor(a1, off);
      a2 += __shfl_xor(a2, off);
    }
    float f = a2 - 1.0f;
    bool g = !done && (f > 1e-6f) && (a1 > 1e-12f);
    if (g) tau += hstep(f, a1, (float)ac); else done = true;
    if (ac <= CAP) { compactable = true; break; }
    if (done) break;
  }

  float* arow = Aout + ((size_t)bh * LROW + r) * LCOL;
  const float* Vb = ValM + (size_t)bh * LCOL * 16;
  float* op = OutWs + ((size_t)bb * LROW + r) * 128 + h * 16;

  if (compactable) {
    // -------- compact survivors via wave prefix-sum --------
    int c = 0;
#pragma unroll
    for (int j = 0; j < J; ++j) c += (x[j] > tau) ? 1 : 0;
    int i = c;
#pragma unroll
    for (int off = 1; off <= 32; off <<= 1) {
      int t = __shfl_up(i, off);
      if (lane >= off) i += t;
    }
    int base = i - c;
    int tot  = __shfl(i, 63);
    int w = 0;
#pragma unroll
    for (int j = 0; j < J; ++j) {
      if (x[j] > tau) {
        sval[ws][base + w] = x[j];
        sidx[ws][base + w] = (unsigned short)(lane + 64 * j);
        ++w;
      }
    }
    __threadfence_block();   // wave-local LDS visibility across lanes

    // -------- compacted solver (<=8 elems/lane) --------
    if (!done) {
      for (int it = 0; it < 24; ++it) {
        float s1 = 0.f, s2 = 0.f;
        int cnt = 0;
        for (int i2 = lane; i2 < tot; i2 += 64) {
          float t = sval[ws][i2] - tau, r0 = fmaxf(t, 0.f);
          s1 += r0; s2 = fmaf(r0, r0, s2);
          cnt += __popcll(__ballot(t > 0.f));
        }
#pragma unroll
        for (int off = 32; off >= 1; off >>= 1) {
          s1 += __shfl_xor(s1, off);
          s2 += __shfl_xor(s2, off);
        }
        float f = s2 - 1.0f;
        bool g = (f > 1e-6f) && (s1 > 1e-12f);
        if (g) tau += hstep(f, s1, (float)cnt); else { done = true; break; }
      }
    }

    // -------- dense A write from live score registers (coalesced) --------
#pragma unroll
    for (int j = 0; j < J; ++j) {
      int kk = lane + 64 * j;
      float t = fmaxf(x[j] - tau, 0.f);
      arow[kk] = t * t;
    }

    // -------- sparse P@V over survivors (all 64 lanes on this row) -------
    float acc[16];
#pragma unroll
    for (int d = 0; d < 16; ++d) acc[d] = 0.f;
    for (int i2 = lane; i2 < tot; i2 += 64) {
      float t = sval[ws][i2] - tau;
      if (t > 0.f) {
        float p = t * t;
        int kk = sidx[ws][i2];
        const float4* vp = (const float4*)(Vb + (size_t)kk * 16);
        float4 v0 = vp[0], v1 = vp[1], v2 = vp[2], v3 = vp[3];
        acc[0]  = fmaf(p, v0.x, acc[0]);  acc[1]  = fmaf(p, v0.y, acc[1]);
        acc[2]  = fmaf(p, v0.z, acc[2]);  acc[3]  = fmaf(p, v0.w, acc[3]);
        acc[4]  = fmaf(p, v1.x, acc[4]);  acc[5]  = fmaf(p, v1.y, acc[5]);
        acc[6]  = fmaf(p, v1.z, acc[6]);  acc[7]  = fmaf(p, v1.w, acc[7]);
        acc[8]  = fmaf(p, v2.x, acc[8]);  acc[9]  = fmaf(p, v2.y, acc[9]);
        acc[10] = fmaf(p, v2.z, acc[10]); acc[11] = fmaf(p, v2.w, acc[11]);
        acc[12] = fmaf(p, v3.x, acc[12]); acc[13] = fmaf(p, v3.y, acc[13]);
        acc[14] = fmaf(p, v3.z, acc[14]); acc[15] = fmaf(p, v3.w, acc[15]);
      }
    }
#pragma unroll
    for (int off = 32; off >= 1; off >>= 1)
#pragma unroll
      for (int d = 0; d < 16; ++d) acc[d] += __shfl_xor(acc[d], off);
    float vv = acc[0];
#pragma unroll
    for (int d = 1; d < 16; ++d)
      vv = (lane == d) ? acc[d] : vv;
    if (lane < 16) op[lane] = vv;
    return;
  }

  // -------- fallback: dense A write + dense P@V (large-support rows) -----
  float acc[16];
#pragma unroll
  for (int d = 0; d < 16; ++d) acc[d] = 0.f;
#pragma unroll
  for (int j = 0; j < J; ++j) {
    int kk = lane + 64 * j;
    float t = fmaxf(x[j] - tau, 0.f), p = t * t;
    arow[kk] = p;
    const float4* vp = (const float4*)(Vb + (size_t)kk * 16);
    float4 v0 = vp[0], v1 = vp[1], v2 = vp[2], v3 = vp[3];
    acc[0]  = fmaf(p, v0.x, acc[0]);  acc[1]  = fmaf(p, v0.y, acc[1]);
    acc[2]  = fmaf(p, v0.z, acc[2]);  acc[3]  = fmaf(p, v0.w, acc[3]);
    acc[4]  = fmaf(p, v1.x, acc[4]);  acc[5]  = fmaf(p, v1.y, acc[5]);
    acc[6]  = fmaf(p, v1.z, acc[6]);  acc[7]  = fmaf(p, v1.w, acc[7]);
    acc[8]  = fmaf(p, v2.x, acc[8]);  acc[9]  = fmaf(p, v2.y, acc[9]);
    acc[10] = fmaf(p, v2.z, acc[10]); acc[11] = fmaf(p, v2.w, acc[11]);
    acc[12] = fmaf(p, v3.x, acc[12]); acc[13] = fmaf(p, v3.y, acc[13]);
    acc[14] = fmaf(p, v3.z, acc[14]); acc[15] = fmaf(p, v3.w, acc[15]);
  }
#pragma unroll
  for (int off = 32; off >= 1; off >>= 1)
#pragma unroll
    for (int d = 0; d < 16; ++d) acc[d] += __shfl_xor(acc[d], off);
  float vv = acc[0];
#pragma unroll
  for (int d = 1; d < 16; ++d)
    vv = (lane == d) ? acc[d] : vv;
  if (lane < 16) op[lane] = vv;
}

// ---------------------------------------------------------------------------
// Fused: Y = X1 @ W1 + bias + X2 @ W2, then LayerNorm(gamma,beta) + ReLU.
// 4 rows per block, 128 threads (one output column each, 2 waves).
// ---------------------------------------------------------------------------
__global__ __launch_bounds__(128) void combine_ln_kernel(
    const float* __restrict__ X1, const float* __restrict__ X2,
    const float* __restrict__ W1, const float* __restrict__ W2,
    const float* __restrict__ bias, const float* __restrict__ gamma,
    const float* __restrict__ beta, float* __restrict__ O)
{
  __shared__ float x1s[4][128], x2s[4][128];
  __shared__ float red[2][8];
  int rb = blockIdx.x * 4;
  int c  = threadIdx.x;
#pragma unroll
  for (int i = 0; i < 4; ++i) {
    x1s[i][c] = X1[(size_t)(rb + i) * 128 + c];
    x2s[i][c] = X2[(size_t)(rb + i) * 128 + c];
  }
  __syncthreads();
  float b = bias[c];
  float a0 = b, a1 = b, a2 = b, a3 = b;
#pragma unroll 4
  for (int d = 0; d < 128; ++d) {
    float w1 = W1[d * 128 + c];
    float w2 = W2[d * 128 + c];
    a0 = fmaf(x1s[0][d], w1, fmaf(x2s[0][d], w2, a0));
    a1 = fmaf(x1s[1][d], w1, fmaf(x2s[1][d], w2, a1));
    a2 = fmaf(x1s[2][d], w1, fmaf(x2s[2][d], w2, a2));
    a3 = fmaf(x1s[3][d], w1, fmaf(x2s[3][d], w2, a3));
  }
  float s0 = a0, s1 = a1, s2 = a2, s3 = a3;
  float q0 = a0 * a0, q1 = a1 * a1, q2 = a2 * a2, q3 = a3 * a3;
#pragma unroll
  for (int off = 32; off >= 1; off >>= 1) {
    s0 += __shfl_xor(s0, off); q0 += __shfl_xor(q0, off);
    s1 += __shfl_xor(s1, off); q1 += __shfl_xor(q1, off);
    s2 += __shfl_xor(s2, off); q2 += __shfl_xor(q2, off);
    s3 += __shfl_xor(s3, off); q3 += __shfl_xor(q3, off);
  }
  int wv = c >> 6;
  if ((c & 63) == 0) {
    red[wv][0] = s0; red[wv][1] = q0; red[wv][2] = s1; red[wv][3] = q1;
    red[wv][4] = s2; red[wv][5] = q2; red[wv][6] = s3; red[wv][7] = q3;
  }
  __syncthreads();
  float S0 = red[0][0] + red[1][0], Q0 = red[0][1] + red[1][1];
  float S1 = red[0][2] + red[1][2], Q1 = red[0][3] + red[1][3];
  float S2 = red[0][4] + red[1][4], Q2 = red[0][5] + red[1][5];
  float S3 = red[0][6] + red[1][6], Q3 = red[0][7] + red[1][7];
  float g = gamma[c], be = beta[c];
  float mu, var, rs;
  mu = S0 * (1.f / 128.f); var = fmaxf(Q0 * (1.f / 128.f) - mu * mu, 0.f);
  rs = rsqrtf(var + 1e-5f);
  O[(size_t)(rb + 0) * 128 + c] = fmaxf(fmaf((a0 - mu) * rs, g, be), 0.f);
  mu = S1 * (1.f / 128.f); var = fmaxf(Q1 * (1.f / 128.f) - mu * mu, 0.f);
  rs = rsqrtf(var + 1e-5f);
  O[(size_t)(rb + 1) * 128 + c] = fmaxf(fmaf((a1 - mu) * rs, g, be), 0.f);
  mu = S2 * (1.f / 128.f); var = fmaxf(Q2 * (1.f / 128.f) - mu * mu, 0.f);
  rs = rsqrtf(var + 1e-5f);
  O[(size_t)(rb + 2) * 128 + c] = fmaxf(fmaf((a2 - mu) * rs, g, be), 0.f);
  mu = S3 * (1.f / 128.f); var = fmaxf(Q3 * (1.f / 128.f) - mu * mu, 0.f);
  rs = rsqrtf(var + 1e-5f);
  O[(size_t)(rb + 3) * 128 + c] = fmaxf(fmaf((a3 - mu) * rs, g, be), 0.f);
}

// ---------------------------------------------------------------------------
extern "C"
__attribute__((visibility("default"), used))
void kernel_launch(void* const* d_in, const int* in_sizes, int n_in,
                   void* d_out, int out_size, void* d_ws, size_t ws_size,
                   hipStream_t stream)
{
  (void)in_sizes; (void)n_in; (void)out_size; (void)ws_size;
  const float* q     = (const float*)d_in[0];
  const float* k     = (const float*)d_in[1];
  const float* v     = (const float*)d_in[2];
  const float* v2    = (const float*)d_in[3];
  const float* W_Q   = (const float*)d_in[4];
  const float* b_Q   = (const float*)d_in[5];
  const float* W_K   = (const float*)d_in[6];
  const float* b_K   = (const float*)d_in[7];
  const float* W_V   = (const float*)d_in[8];
  const float* b_V   = (const float*)d_in[9];
  const float* W_V2  = (const float*)d_in[10];
  const float* b_V2  = (const float*)d_in[11];
  const float* W_O   = (const float*)d_in[12];
  const float* b_O   = (const float*)d_in[13];
  const float* W_O2  = (const float*)d_in[14];
  const float* b_O2  = (const float*)d_in[15];
  const float* W_R   = (const float*)d_in[16];
  const float* W_R2  = (const float*)d_in[17];
  const float* gamma = (const float*)d_in[18];
  const float* beta  = (const float*)d_in[19];

  char* ws = (char*)d_ws;
  const size_t MB = 1u << 20;
  float* Qp    = (float*)(ws + 0);        // chunk-major [bh][4][1024][4]
  float* Kp    = (float*)(ws + 2 * MB);   // chunk-major [bh][4][2048][4]
  float* Vp    = (float*)(ws + 6 * MB);   // row-major   [bh][2048][16]
  float* V2p   = (float*)(ws + 10 * MB);  // row-major   [bh][1024][16]
  float* outm1 = (float*)(ws + 12 * MB);
  float* outm2 = (float*)(ws + 14 * MB);

  float* out1  = (float*)d_out;              // (4,1024,128)
  float* out2  = out1 + (size_t)524288;      // (4,2048,128)
  float* Aout  = out1 + (size_t)1572864;     // (4,8,1024,2048)
  float* A2out = out1 + (size_t)68681728;    // (4,8,2048,1024)

  proj_all_kernel<<<6144, 128, 0, stream>>>(
      q, k, v, v2, W_Q, b_Q, W_K, b_K, W_V, b_V, W_V2, b_V2,
      Qp, Kp, Vp, V2p);

  attn_kernel<1024, 2048, 4><<<8192,  256, 0, stream>>>(Qp, Kp, Vp,  Aout,  outm1);
  attn_kernel<2048, 1024, 5><<<16384, 256, 0, stream>>>(Kp, Qp, V2p, A2out, outm2);

  combine_ln_kernel<<<1024, 128, 0, stream>>>(outm1, q, W_O,  W_R,  b_O,
                                              gamma, beta, out1);
  combine_ln_kernel<<<2048, 128, 0, stream>>>(outm2, k, W_O2, W_R2, b_O2,
                                              gamma, beta, out2);
}

// Round 5
// 1066.369 us; speedup vs baseline: 1.3967x; 1.1224x over previous
//
#include <hip/hip_runtime.h>

// ---------------------------------------------------------------------------
// All four projections in one launch. 4 rows per block, 128 threads.
// CHUNKED=0: Y[((bb*8+h)*L + l)*16 + dd]                      (row layout, V)
// CHUNKED=1: Y[(((bb*8+h)*4 + dd/4)*L + l)*4 + dd%4]   (chunk-major, Q and K)
// ---------------------------------------------------------------------------
__global__ __launch_bounds__(128) void proj_all_kernel(
    const float* __restrict__ q, const float* __restrict__ k,
    const float* __restrict__ v, const float* __restrict__ v2,
    const float* __restrict__ W_Q, const float* __restrict__ b_Q,
    const float* __restrict__ W_K, const float* __restrict__ b_K,
    const float* __restrict__ W_V, const float* __restrict__ b_V,
    const float* __restrict__ W_V2, const float* __restrict__ b_V2,
    float* __restrict__ Qp, float* __restrict__ Kp,
    float* __restrict__ Vp, float* __restrict__ V2p)
{
  __shared__ float xs[4][128];
  int blk = blockIdx.x;
  const float *X, *W, *B; float* Y; int L, chunked, rb;
  if (blk < 1024)      { X = q;  W = W_Q;  B = b_Q;  Y = Qp;  L = 1024; chunked = 1; rb = blk; }
  else if (blk < 3072) { X = k;  W = W_K;  B = b_K;  Y = Kp;  L = 2048; chunked = 1; rb = blk - 1024; }
  else if (blk < 5120) { X = v;  W = W_V;  B = b_V;  Y = Vp;  L = 2048; chunked = 0; rb = blk - 3072; }
  else                 { X = v2; W = W_V2; B = b_V2; Y = V2p; L = 1024; chunked = 0; rb = blk - 5120; }
  rb *= 4;
  int c = threadIdx.x;
#pragma unroll
  for (int i = 0; i < 4; ++i)
    xs[i][c] = X[(size_t)(rb + i) * 128 + c];
  __syncthreads();
  float b = B[c];
  float a0 = b, a1 = b, a2 = b, a3 = b;
#pragma unroll 8
  for (int d = 0; d < 128; ++d) {
    float w = W[d * 128 + c];
    a0 = fmaf(xs[0][d], w, a0);
    a1 = fmaf(xs[1][d], w, a1);
    a2 = fmaf(xs[2][d], w, a2);
    a3 = fmaf(xs[3][d], w, a3);
  }
  int h = c >> 4, dd = c & 15;
  float av[4] = { a0, a1, a2, a3 };
#pragma unroll
  for (int i = 0; i < 4; ++i) {
    int row = rb + i;
    int bb = row / L;
    int l  = row - bb * L;
    if (chunked)
      Y[(((size_t)(bb * 8 + h) * 4 + (dd >> 2)) * L + l) * 4 + (dd & 3)] = av[i];
    else
      Y[((size_t)(bb * 8 + h) * L + l) * 16 + dd] = av[i];
  }
}

// Guarded hybrid root step for f(u-shifted) = S2 - 1 over current support:
// exact segment root when discriminant real, else Newton.
static __device__ __forceinline__ float hstep(float f, float s1, float cnt)
{
  float arg = fmaf(-cnt, f, s1 * s1);
  return (arg > 0.f) ? f / (s1 + sqrtf(arg)) : f / (2.f * s1);
}

// ---------------------------------------------------------------------------
// Attention pass (fp32). ONE WAVE PER ROW, no forced occupancy cap (round-3/4
// lesson: launch_bounds min-waves below natural VGPR usage => scratch spill
// => GBs of HBM spill traffic).
//
// FAST PATH (statistical threshold, verified): one pass gives row max m,
// mean mu, std sig. theta = max(mu + Z*sig, m-1) is a high-probability
// LOWER bound on tau* (true support ~5% of row; theta keeps ~16%). Compact
// survivors {x > theta} DIRECTLY (zero dense solver sweeps), run the
// monotone hybrid solver on the compacted set starting at theta. Validity
// is checked, not assumed: iteration 0 computes the true global
// f(theta) = S2(theta) - 1 (excluded cols contribute 0 since x <= theta).
// If f < -1e-6 (theta overshot tau*), or count==0, or count > CAP, fall
// back to the full dense solve from m-1. Accepted path: tau >= theta, so
// excluded columns have (x - tau)+ = 0 -> identical math to dense.
// ---------------------------------------------------------------------------
template<int LROW, int LCOL>
__global__ __launch_bounds__(256) void attn_kernel(
    const float* __restrict__ RowM, const float* __restrict__ ColM,
    const float* __restrict__ ValM, float* __restrict__ Aout,
    float* __restrict__ OutWs)
{
  constexpr int J   = LCOL / 64;
  constexpr int CAP = 512;
  constexpr float Z = 1.0f;
  __shared__ float          sval[4][CAP];
  __shared__ unsigned short sidx[4][CAP];

  int ws   = threadIdx.x >> 6;                      // wave slot in block
  int wid  = blockIdx.x * 4 + ws;                   // global row id
  int lane = threadIdx.x & 63;
  int bh   = wid / LROW;
  int r    = wid - bh * LROW;
  int bb   = bh >> 3, h = bh & 7;

  float qf[16];
  { const float* qb = RowM + (size_t)bh * LROW * 16;   // chunk-major block
#pragma unroll
    for (int d = 0; d < 16; ++d)
      qf[d] = qb[((size_t)(d >> 2) * LROW + r) * 4 + (d & 3)] * 0.125f;
  }

  // -------- scores (raw) --------
  float x[J];
  const float4* Cb = (const float4*)(ColM + (size_t)bh * LCOL * 16);
#pragma unroll
  for (int j = 0; j < J; ++j) {
    int kk = lane + 64 * j;
    float4 k0 = Cb[0 * LCOL + kk];      // 16B/lane contiguous -> 1KB/wave
    float  s  = qf[0] * k0.x;
    s = fmaf(qf[1], k0.y, s); s = fmaf(qf[2], k0.z, s); s = fmaf(qf[3], k0.w, s);
    float4 k1 = Cb[1 * LCOL + kk];
    s = fmaf(qf[4], k1.x, s); s = fmaf(qf[5], k1.y, s);
    s = fmaf(qf[6], k1.z, s); s = fmaf(qf[7], k1.w, s);
    float4 k2 = Cb[2 * LCOL + kk];
    s = fmaf(qf[8], k2.x, s); s = fmaf(qf[9], k2.y, s);
    s = fmaf(qf[10], k2.z, s); s = fmaf(qf[11], k2.w, s);
    float4 k3 = Cb[3 * LCOL + kk];
    s = fmaf(qf[12], k3.x, s); s = fmaf(qf[13], k3.y, s);
    s = fmaf(qf[14], k3.z, s); s = fmaf(qf[15], k3.w, s);
    x[j] = s;
  }

  // -------- one-pass stats: max, sum, sumsq --------
  float m = -1e30f, sr = 0.f, qr = 0.f;
#pragma unroll
  for (int j = 0; j < J; ++j) {
    m = fmaxf(m, x[j]);
    sr += x[j];
    qr = fmaf(x[j], x[j], qr);
  }
#pragma unroll
  for (int off = 32; off >= 1; off >>= 1) {
    m  = fmaxf(m, __shfl_xor(m, off));
    sr += __shfl_xor(sr, off);
    qr += __shfl_xor(qr, off);
  }
  float mu  = sr * (1.f / (float)LCOL);
  float sig = sqrtf(fmaxf(qr * (1.f / (float)LCOL) - mu * mu, 0.f));
  float theta = fmaxf(fmaf(Z, sig, mu), m - 1.0f);

  float* arow = Aout + ((size_t)bh * LROW + r) * LCOL;
  const float* Vb = ValM + (size_t)bh * LCOL * 16;
  float* op = OutWs + ((size_t)bb * LROW + r) * 128 + h * 16;

  // -------- survivor count + compaction at theta --------
  int c = 0;
#pragma unroll
  for (int j = 0; j < J; ++j) c += (x[j] > theta) ? 1 : 0;
  int i = c;
#pragma unroll
  for (int off = 1; off <= 32; off <<= 1) {
    int t = __shfl_up(i, off);
    if (lane >= off) i += t;
  }
  int base = i - c;
  int tot  = __shfl(i, 63);

  if (tot >= 1 && tot <= CAP) {
    int w = 0;
#pragma unroll
    for (int j = 0; j < J; ++j) {
      if (x[j] > theta) {
        sval[ws][base + w] = x[j];
        sidx[ws][base + w] = (unsigned short)(lane + 64 * j);
        ++w;
      }
    }
    __threadfence_block();   // wave-local LDS visibility across lanes

    // -------- compacted monotone solver from theta, validity-checked ----
    float tau = theta;
    bool valid = true;
    for (int it = 0; it < 24; ++it) {
      float s1 = 0.f, s2 = 0.f;
      int cnt = 0;
      for (int i2 = lane; i2 < tot; i2 += 64) {
        float t = sval[ws][i2] - tau, r0 = fmaxf(t, 0.f);
        s1 += r0; s2 = fmaf(r0, r0, s2);
        cnt += __popcll(__ballot(t > 0.f));
      }
#pragma unroll
      for (int off = 32; off >= 1; off >>= 1) {
        s1 += __shfl_xor(s1, off);
        s2 += __shfl_xor(s2, off);
      }
      float f = s2 - 1.0f;
      if (it == 0 && f < -1e-6f) { valid = false; break; }  // theta > tau*
      if (f > 1e-6f && s1 > 1e-12f) tau += hstep(f, s1, (float)cnt);
      else break;                                           // converged
    }

    if (valid) {
      // -------- dense A write from live score registers (coalesced) ----
#pragma unroll
      for (int j = 0; j < J; ++j) {
        int kk = lane + 64 * j;
        float t = fmaxf(x[j] - tau, 0.f);
        arow[kk] = t * t;
      }

      // -------- sparse P@V over survivors --------
      float acc[16];
#pragma unroll
      for (int d = 0; d < 16; ++d) acc[d] = 0.f;
      for (int i2 = lane; i2 < tot; i2 += 64) {
        float t = sval[ws][i2] - tau;
        if (t > 0.f) {
          float p = t * t;
          int kk = sidx[ws][i2];
          const float4* vp = (const float4*)(Vb + (size_t)kk * 16);
          float4 v0 = vp[0], v1 = vp[1], v2 = vp[2], v3 = vp[3];
          acc[0]  = fmaf(p, v0.x, acc[0]);  acc[1]  = fmaf(p, v0.y, acc[1]);
          acc[2]  = fmaf(p, v0.z, acc[2]);  acc[3]  = fmaf(p, v0.w, acc[3]);
          acc[4]  = fmaf(p, v1.x, acc[4]);  acc[5]  = fmaf(p, v1.y, acc[5]);
          acc[6]  = fmaf(p, v1.z, acc[6]);  acc[7]  = fmaf(p, v1.w, acc[7]);
          acc[8]  = fmaf(p, v2.x, acc[8]);  acc[9]  = fmaf(p, v2.y, acc[9]);
          acc[10] = fmaf(p, v2.z, acc[10]); acc[11] = fmaf(p, v2.w, acc[11]);
          acc[12] = fmaf(p, v3.x, acc[12]); acc[13] = fmaf(p, v3.y, acc[13]);
          acc[14] = fmaf(p, v3.z, acc[14]); acc[15] = fmaf(p, v3.w, acc[15]);
        }
      }
#pragma unroll
      for (int off = 32; off >= 1; off >>= 1)
#pragma unroll
        for (int d = 0; d < 16; ++d) acc[d] += __shfl_xor(acc[d], off);
      float vv = acc[0];
#pragma unroll
      for (int d = 1; d < 16; ++d)
        vv = (lane == d) ? acc[d] : vv;
      if (lane < 16) op[lane] = vv;
      return;
    }
  }

  // ============ FALLBACK (rare): full dense solve from m-1 ==============
  float tau = m - 1.0f;
  bool done = false;
  for (int it = 0; it < 24; ++it) {
    float a1 = 0.f, a2 = 0.f;
    int ac = 0;
#pragma unroll
    for (int j = 0; j < J; ++j) {
      float t = x[j] - tau, r0 = fmaxf(t, 0.f);
      a1 += r0; a2 = fmaf(r0, r0, a2);
      ac += __popcll(__ballot(t > 0.f));
    }
#pragma unroll
    for (int off = 32; off >= 1; off >>= 1) {
      a1 += __shfl_xor(a1, off);
      a2 += __shfl_xor(a2, off);
    }
    float f = a2 - 1.0f;
    bool g = !done && (f > 1e-6f) && (a1 > 1e-12f);
    if (g) tau += hstep(f, a1, (float)ac); else done = true;
    if (done) break;
  }

  float acc[16];
#pragma unroll
  for (int d = 0; d < 16; ++d) acc[d] = 0.f;
#pragma unroll
  for (int j = 0; j < J; ++j) {
    int kk = lane + 64 * j;
    float t = fmaxf(x[j] - tau, 0.f), p = t * t;
    arow[kk] = p;
    const float4* vp = (const float4*)(Vb + (size_t)kk * 16);
    float4 v0 = vp[0], v1 = vp[1], v2 = vp[2], v3 = vp[3];
    acc[0]  = fmaf(p, v0.x, acc[0]);  acc[1]  = fmaf(p, v0.y, acc[1]);
    acc[2]  = fmaf(p, v0.z, acc[2]);  acc[3]  = fmaf(p, v0.w, acc[3]);
    acc[4]  = fmaf(p, v1.x, acc[4]);  acc[5]  = fmaf(p, v1.y, acc[5]);
    acc[6]  = fmaf(p, v1.z, acc[6]);  acc[7]  = fmaf(p, v1.w, acc[7]);
    acc[8]  = fmaf(p, v2.x, acc[8]);  acc[9]  = fmaf(p, v2.y, acc[9]);
    acc[10] = fmaf(p, v2.z, acc[10]); acc[11] = fmaf(p, v2.w, acc[11]);
    acc[12] = fmaf(p, v3.x, acc[12]); acc[13] = fmaf(p, v3.y, acc[13]);
    acc[14] = fmaf(p, v3.z, acc[14]); acc[15] = fmaf(p, v3.w, acc[15]);
  }
#pragma unroll
  for (int off = 32; off >= 1; off >>= 1)
#pragma unroll
    for (int d = 0; d < 16; ++d) acc[d] += __shfl_xor(acc[d], off);
  float vv = acc[0];
#pragma unroll
  for (int d = 1; d < 16; ++d)
    vv = (lane == d) ? acc[d] : vv;
  if (lane < 16) op[lane] = vv;
}

// ---------------------------------------------------------------------------
// Fused: Y = X1 @ W1 + bias + X2 @ W2, then LayerNorm(gamma,beta) + ReLU.
// 4 rows per block, 128 threads (one output column each, 2 waves).
// ---------------------------------------------------------------------------
__global__ __launch_bounds__(128) void combine_ln_kernel(
    const float* __restrict__ X1, const float* __restrict__ X2,
    const float* __restrict__ W1, const float* __restrict__ W2,
    const float* __restrict__ bias, const float* __restrict__ gamma,
    const float* __restrict__ beta, float* __restrict__ O)
{
  __shared__ float x1s[4][128], x2s[4][128];
  __shared__ float red[2][8];
  int rb = blockIdx.x * 4;
  int c  = threadIdx.x;
#pragma unroll
  for (int i = 0; i < 4; ++i) {
    x1s[i][c] = X1[(size_t)(rb + i) * 128 + c];
    x2s[i][c] = X2[(size_t)(rb + i) * 128 + c];
  }
  __syncthreads();
  float b = bias[c];
  float a0 = b, a1 = b, a2 = b, a3 = b;
#pragma unroll 8
  for (int d = 0; d < 128; ++d) {
    float w1 = W1[d * 128 + c];
    float w2 = W2[d * 128 + c];
    a0 = fmaf(x1s[0][d], w1, fmaf(x2s[0][d], w2, a0));
    a1 = fmaf(x1s[1][d], w1, fmaf(x2s[1][d], w2, a1));
    a2 = fmaf(x1s[2][d], w1, fmaf(x2s[2][d], w2, a2));
    a3 = fmaf(x1s[3][d], w1, fmaf(x2s[3][d], w2, a3));
  }
  float s0 = a0, s1 = a1, s2 = a2, s3 = a3;
  float q0 = a0 * a0, q1 = a1 * a1, q2 = a2 * a2, q3 = a3 * a3;
#pragma unroll
  for (int off = 32; off >= 1; off >>= 1) {
    s0 += __shfl_xor(s0, off); q0 += __shfl_xor(q0, off);
    s1 += __shfl_xor(s1, off); q1 += __shfl_xor(q1, off);
    s2 += __shfl_xor(s2, off); q2 += __shfl_xor(q2, off);
    s3 += __shfl_xor(s3, off); q3 += __shfl_xor(q3, off);
  }
  int wv = c >> 6;
  if ((c & 63) == 0) {
    red[wv][0] = s0; red[wv][1] = q0; red[wv][2] = s1; red[wv][3] = q1;
    red[wv][4] = s2; red[wv][5] = q2; red[wv][6] = s3; red[wv][7] = q3;
  }
  __syncthreads();
  float S0 = red[0][0] + red[1][0], Q0 = red[0][1] + red[1][1];
  float S1 = red[0][2] + red[1][2], Q1 = red[0][3] + red[1][3];
  float S2 = red[0][4] + red[1][4], Q2 = red[0][5] + red[1][5];
  float S3 = red[0][6] + red[1][6], Q3 = red[0][7] + red[1][7];
  float g = gamma[c], be = beta[c];
  float mu, var, rs;
  mu = S0 * (1.f / 128.f); var = fmaxf(Q0 * (1.f / 128.f) - mu * mu, 0.f);
  rs = rsqrtf(var + 1e-5f);
  O[(size_t)(rb + 0) * 128 + c] = fmaxf(fmaf((a0 - mu) * rs, g, be), 0.f);
  mu = S1 * (1.f / 128.f); var = fmaxf(Q1 * (1.f / 128.f) - mu * mu, 0.f);
  rs = rsqrtf(var + 1e-5f);
  O[(size_t)(rb + 1) * 128 + c] = fmaxf(fmaf((a1 - mu) * rs, g, be), 0.f);
  mu = S2 * (1.f / 128.f); var = fmaxf(Q2 * (1.f / 128.f) - mu * mu, 0.f);
  rs = rsqrtf(var + 1e-5f);
  O[(size_t)(rb + 2) * 128 + c] = fmaxf(fmaf((a2 - mu) * rs, g, be), 0.f);
  mu = S3 * (1.f / 128.f); var = fmaxf(Q3 * (1.f / 128.f) - mu * mu, 0.f);
  rs = rsqrtf(var + 1e-5f);
  O[(size_t)(rb + 3) * 128 + c] = fmaxf(fmaf((a3 - mu) * rs, g, be), 0.f);
}

// ---------------------------------------------------------------------------
extern "C"
__attribute__((visibility("default"), used))
void kernel_launch(void* const* d_in, const int* in_sizes, int n_in,
                   void* d_out, int out_size, void* d_ws, size_t ws_size,
                   hipStream_t stream)
{
  (void)in_sizes; (void)n_in; (void)out_size; (void)ws_size;
  const float* q     = (const float*)d_in[0];
  const float* k     = (const float*)d_in[1];
  const float* v     = (const float*)d_in[2];
  const float* v2    = (const float*)d_in[3];
  const float* W_Q   = (const float*)d_in[4];
  const float* b_Q   = (const float*)d_in[5];
  const float* W_K   = (const float*)d_in[6];
  const float* b_K   = (const float*)d_in[7];
  const float* W_V   = (const float*)d_in[8];
  const float* b_V   = (const float*)d_in[9];
  const float* W_V2  = (const float*)d_in[10];
  const float* b_V2  = (const float*)d_in[11];
  const float* W_O   = (const float*)d_in[12];
  const float* b_O   = (const float*)d_in[13];
  const float* W_O2  = (const float*)d_in[14];
  const float* b_O2  = (const float*)d_in[15];
  const float* W_R   = (const float*)d_in[16];
  const float* W_R2  = (const float*)d_in[17];
  const float* gamma = (const float*)d_in[18];
  const float* beta  = (const float*)d_in[19];

  char* ws = (char*)d_ws;
  const size_t MB = 1u << 20;
  float* Qp    = (float*)(ws + 0);        // chunk-major [bh][4][1024][4]
  float* Kp    = (float*)(ws + 2 * MB);   // chunk-major [bh][4][2048][4]
  float* Vp    = (float*)(ws + 6 * MB);   // row-major   [bh][2048][16]
  float* V2p   = (float*)(ws + 10 * MB);  // row-major   [bh][1024][16]
  float* outm1 = (float*)(ws + 12 * MB);
  float* outm2 = (float*)(ws + 14 * MB);

  float* out1  = (float*)d_out;              // (4,1024,128)
  float* out2  = out1 + (size_t)524288;      // (4,2048,128)
  float* Aout  = out1 + (size_t)1572864;     // (4,8,1024,2048)
  float* A2out = out1 + (size_t)68681728;    // (4,8,2048,1024)

  proj_all_kernel<<<6144, 128, 0, stream>>>(
      q, k, v, v2, W_Q, b_Q, W_K, b_K, W_V, b_V, W_V2, b_V2,
      Qp, Kp, Vp, V2p);

  attn_kernel<1024, 2048><<<8192,  256, 0, stream>>>(Qp, Kp, Vp,  Aout,  outm1);
  attn_kernel<2048, 1024><<<16384, 256, 0, stream>>>(Kp, Qp, V2p, A2out, outm2);

  combine_ln_kernel<<<1024, 128, 0, stream>>>(outm1, q, W_O,  W_R,  b_O,
                                              gamma, beta, out1);
  combine_ln_kernel<<<2048, 128, 0, stream>>>(outm2, k, W_O2, W_R2, b_O2,
                                              gamma, beta, out2);
}